// Round 11
// baseline (186.934 us; speedup 1.0000x reference)
//
#include <hip/hip_runtime.h>
#include <hip/hip_bf16.h>

#define NPTS   2048
#define IDIM   16
#define HDIM   32
#define CUTSN  8
#define EPSV   1e-5f
#define PSCALE 0.07856742013183862f   /* 1/(sqrt(2)*9) */
#define ICH    8                      /* i-rows per block chunk (2 per MFMA) */
#define IPK    48                     /* floats per ipack row (192B aligned) */

typedef __bf16 bf16x8 __attribute__((ext_vector_type(8)));
typedef __bf16 bf16x4 __attribute__((ext_vector_type(4)));
typedef float  f32x16 __attribute__((ext_vector_type(16)));

__device__ __forceinline__ float leaky(float x) { return x >= 0.f ? x : 0.2f * x; }

/* ------- two-layer MLP (per-row) + GroupNorm partial sums (+ipack/zero) -------
 * 32 blocks x 64 threads (one wave), one row per thread. partials (256 floats):
 * [g*32 + block] = group sums, [128 + g*32 + block] = group sumsq.
 * ipack row (40 used of 48):
 *   c=0..7 : {Mx,My,Mz,bias'}  M_c = A1_c @ nuv_i, bias' = B1_c - M_c.(s p_i)
 *   [32..35]: {-2 s p_i, q_i}   q_i = |s p_i|^2
 *   [36..39]: {n_i, 0}                                              */
template <int K>
__global__ __launch_bounds__(64) void net2_kernel(
    const float* __restrict__ xin,
    const float* __restrict__ W1, const float* __restrict__ b1,
    const float* __restrict__ W2, const float* __restrict__ b2,
    float* __restrict__ out, float* __restrict__ partials,
    float* __restrict__ zbuf,
    const float* __restrict__ points, const float* __restrict__ nuv,
    const float* __restrict__ A1, const float* __restrict__ B1,
    float* __restrict__ ipack)
{
    const int t = threadIdx.x;
    const int i = blockIdx.x * 64 + t;
    if (zbuf) {
#pragma unroll
        for (int e = 0; e < 8; ++e)
            *(float4*)&zbuf[i * HDIM + e * 4] = make_float4(0.f, 0.f, 0.f, 0.f);
    }
    if (ipack) {
        float* ip = ipack + i * IPK;
        const float spx = points[i * 3 + 0] * PSCALE;
        const float spy = points[i * 3 + 1] * PSCALE;
        const float spz = points[i * 3 + 2] * PSCALE;
#pragma unroll
        for (int c = 0; c < 8; ++c) {
            float m0 = 0.f, m1 = 0.f, m2 = 0.f;
#pragma unroll
            for (int a = 0; a < 3; ++a) {
                const float wA = A1[c * 3 + a];
                m0 = fmaf(wA, nuv[i * 9 + a * 3 + 0], m0);
                m1 = fmaf(wA, nuv[i * 9 + a * 3 + 1], m1);
                m2 = fmaf(wA, nuv[i * 9 + a * 3 + 2], m2);
            }
            const float bp = B1[c] - (m0 * spx + m1 * spy + m2 * spz);
            *(float4*)&ip[c * 4] = make_float4(m0, m1, m2, bp);
        }
        *(float4*)&ip[32] = make_float4(-2.f * spx, -2.f * spy, -2.f * spz,
                                        spx * spx + spy * spy + spz * spz);
        *(float4*)&ip[36] = make_float4(nuv[i * 9 + 0], nuv[i * 9 + 1],
                                        nuv[i * 9 + 2], 0.f);
        *(float4*)&ip[40] = make_float4(0.f, 0.f, 0.f, 0.f);
        *(float4*)&ip[44] = make_float4(0.f, 0.f, 0.f, 0.f);
    }

    float x[K];
#pragma unroll
    for (int k = 0; k < K; ++k) x[k] = xin[i * K + k];

    float y[HDIM];
#pragma unroll
    for (int h = 0; h < HDIM; ++h) {
        float v = b1[h];
#pragma unroll
        for (int k = 0; k < K; ++k) v = fmaf(x[k], W1[h * K + k], v);
        y[h] = leaky(v);
    }
    float ps[4]  = {0.f, 0.f, 0.f, 0.f};
    float pss[4] = {0.f, 0.f, 0.f, 0.f};
#pragma unroll
    for (int h = 0; h < HDIM; ++h) {
        float v = b2[h];
#pragma unroll
        for (int k = 0; k < HDIM; ++k) v = fmaf(y[k], W2[h * HDIM + k], v);
        v = leaky(v);
        out[i * HDIM + h] = v;
        const int g = h >> 3;                 /* compile-time after unroll */
        ps[g] += v; pss[g] = fmaf(v, v, pss[g]);
    }
#pragma unroll
    for (int off = 32; off; off >>= 1) {
#pragma unroll
        for (int g = 0; g < 4; ++g) {
            ps[g]  += __shfl_down(ps[g],  off, 64);
            pss[g] += __shfl_down(pss[g], off, 64);
        }
    }
    if (t == 0) {
#pragma unroll
        for (int g = 0; g < 4; ++g) {
            partials[g * 32 + blockIdx.x]       = ps[g];
            partials[128 + g * 32 + blockIdx.x] = pss[g];
        }
    }
}

/* ------- GroupNorm apply (final output): reduces block-partials inline ------- */
__global__ __launch_bounds__(256) void gn_apply_kernel(
    const float* __restrict__ x, const float* __restrict__ partials,
    const float* __restrict__ gw, const float* __restrict__ gb,
    float* __restrict__ out)
{
    const int idx = blockIdx.x * 256 + threadIdx.x;   /* < NPTS*HDIM */
    const int c = idx & (HDIM - 1);
    const int g = c >> 3;
    float s = 0.f, q = 0.f;
#pragma unroll
    for (int b = 0; b < 32; ++b) {
        s += partials[g * 32 + b];
        q += partials[128 + g * 32 + b];
    }
    const float inv = 1.f / (8.f * NPTS);
    const float mu = s * inv;
    const float rs = rsqrtf(q * inv - mu * mu + EPSV);
    out[idx] = fmaf((x[idx] - mu) * rs, gw[c], gb[c]);
}

/* =============== N^2 pairwise: 3-MFMA super-iteration (2 i x 32 j) ===========
 * grid (8, 256): x -> 256-j group (8 waves x 32 j), y -> 8-i chunk.
 * Per super-iter s (i0 = ibase+2s, i1 = i0+1), each wave does:
 *  (1) GEOMETRY MFMA: A = M-rows (row=(c&3)+8*(c>>2)+4*i_sel, k={.,.,.,.}=
 *      {Mx,My,Mz,bias'} bf16, rows 16-31 = 0), B = per-lane {pj,1} bf16.
 *      D layout (col=lane&31=j, row=(r&3)+8*(r>>2)+4*khalf) delivers each
 *      lane its OWN i's cuts c0..7 in d[0..7] (khalf0<->i0, khalf1<->i1).
 *  (2) window w (f32 VALU, per-lane own i via khalf-select of s_loaded G8/G9);
 *      u[e] = w*relu(cut[e]); one __shfl_xor(w,32) moves w across halves for
 *      the bias slots.
 *  (3) TWO matvec MFMAs with khalf-mirrored A/B frags:
 *      i0: afrag = khalf0? u_i0 : {w_i0,0..}; B rows 0-7=A2, 8=B2, 9-15=0.
 *      i1: afrag = khalf0? {w_i1,0..} : u_i1; B rows 0=B2, 1-7=0, 8-15=A2.
 *      Post: acc_i += relu(d)*freg  (16 rows/lane; lane pairs cover 32 j).
 * Replaces ~550 VALU/64-pairs (r10) with ~120 VALU + 3 MFMA + 1 ds_read.
 * All register arrays static-indexed (rule #20); launch_bounds(512,1) = 256
 * VGPR cap (spill lessons r2-4); no sched fences (r9/r10 lesson). */
__global__ __launch_bounds__(512, 1) void pairwise_kernel(
    const float* __restrict__ points, const float* __restrict__ nuv,
    const float* __restrict__ A2, const float* __restrict__ B2,
    const float* __restrict__ ipack,
    const float* __restrict__ traw, const float* __restrict__ partials,
    const float* __restrict__ gw, const float* __restrict__ gb,
    float* __restrict__ fout)
{
    const int t     = threadIdx.x;
    const int lane  = t & 63;
    const int h     = lane & 31;          /* B/D column; local j */
    const bool kh   = (lane >> 5) != 0;
    const int khalf = lane >> 5;
    const int ibase = blockIdx.y * ICH;
    const int jt0   = blockIdx.x * 256 + (t >> 6) * 32;

    __shared__ float  sacc[ICH][32];          /* 1 KB tile accumulator */
    __shared__ bf16x4 sM[ICH / 2][32];        /* geo A-frag rows, bf16 */

    if (t < ICH * 32) ((float*)sacc)[t] = 0.f;

    /* ---- stage geo A-frag rows (128 entries of 8B) ---- */
    if (t < (ICH / 2) * 32) {
        const int s = t >> 5, row = t & 31;
        bf16x4 mv;
        if (row < 16) {
            const int isel = (row >> 2) & 1;
            const int c    = (row & 3) + 4 * (row >> 3);
            const int i    = ibase + 2 * s + isel;
            const float4 m = *(const float4*)&ipack[i * IPK + c * 4];
            mv[0] = (__bf16)m.x; mv[1] = (__bf16)m.y;
            mv[2] = (__bf16)m.z; mv[3] = (__bf16)m.w;
        } else {
            mv[0] = (__bf16)0.f; mv[1] = (__bf16)0.f;
            mv[2] = (__bf16)0.f; mv[3] = (__bf16)0.f;
        }
        sM[t >> 5][row] = mv;
    }

    /* ---- per-lane j-side ---- */
    const int j = jt0 + h;
    const float pjx = points[j * 3 + 0] * PSCALE;
    const float pjy = points[j * 3 + 1] * PSCALE;
    const float pjz = points[j * 3 + 2] * PSCALE;
    const float njx = nuv[j * 9 + 0], njy = nuv[j * 9 + 1], njz = nuv[j * 9 + 2];
    const float qj  = fmaf(pjx, pjx, fmaf(pjy, pjy, pjz * pjz));

    /* geometry B fragment: k0-3 = {pj,1} on khalf0; everything else 0 */
    bf16x8 bgeo;
    bgeo[0] = kh ? (__bf16)0.f : (__bf16)pjx;
    bgeo[1] = kh ? (__bf16)0.f : (__bf16)pjy;
    bgeo[2] = kh ? (__bf16)0.f : (__bf16)pjz;
    bgeo[3] = kh ? (__bf16)0.f : (__bf16)1.f;
#pragma unroll
    for (int e = 4; e < 8; ++e) bgeo[e] = (__bf16)0.f;

    /* matvec B fragments (khalf-mirrored) */
    bf16x8 bM0, bM1;
    {
        const __bf16 b2h = (__bf16)B2[h];
        const __bf16 zb  = (__bf16)0.f;
#pragma unroll
        for (int e = 0; e < 8; ++e) {
            const __bf16 a2v   = (__bf16)A2[h * 8 + e];
            const __bf16 wslot = (e == 0) ? b2h : zb;
            bM0[e] = kh ? wslot : a2v;
            bM1[e] = kh ? a2v : wslot;
        }
    }

    /* ---- GroupNorm-on-the-fly f registers (16 per lane) ---- */
    const int g4 = h >> 3;
    float s = 0.f, q = 0.f;
#pragma unroll
    for (int b = 0; b < 32; ++b) {
        s += partials[g4 * 32 + b];
        q += partials[128 + g4 * 32 + b];
    }
    const float inv = 1.f / (8.f * NPTS);
    const float mu = s * inv;
    const float rs = rsqrtf(q * inv - mu * mu + EPSV);
    const float alpha = rs * gw[h];
    const float gamma = fmaf(-mu, alpha, gb[h]);
    float freg[16];
#pragma unroll
    for (int r = 0; r < 16; ++r) {
        const int jr = (r & 3) + 8 * (r >> 2) + 4 * khalf;  /* D row for reg r */
        freg[r] = fmaf(traw[(jt0 + jr) * HDIM + h], alpha, gamma);
    }

    f32x16 czero;
#pragma unroll
    for (int e = 0; e < 16; ++e) czero[e] = 0.f;

    float accv[ICH];
#pragma unroll
    for (int il = 0; il < ICH; ++il) accv[il] = 0.f;

    __syncthreads();

    /* ---- main loop: ICH/2 super-iterations, fully unrolled (static idx) ---- */
#pragma unroll
    for (int si = 0; si < ICH / 2; ++si) {
        /* s_load both i's window params (wave-uniform) */
        const float4* ipA = (const float4*)(ipack + (ibase + 2 * si) * IPK);
        const float4* ipB = (const float4*)(ipack + (ibase + 2 * si + 1) * IPK);
        const float4 G80 = ipA[8], G90 = ipA[9];
        const float4 G81 = ipB[8], G91 = ipB[9];

        /* own-i window (khalf-select the scalar params) */
        const float g8x = kh ? G81.x : G80.x;
        const float g8y = kh ? G81.y : G80.y;
        const float g8z = kh ? G81.z : G80.z;
        const float g8w = kh ? G81.w : G80.w;
        const float g9x = kh ? G91.x : G90.x;
        const float g9y = kh ? G91.y : G90.y;
        const float g9z = kh ? G91.z : G90.z;
        const float sq = fmaf(g8x, pjx, fmaf(g8y, pjy, fmaf(g8z, pjz, g8w))) + qj;
        const float dt = fmaf(g9x, njx, fmaf(g9y, njy, g9z * njz));
        const float tt = 2.f - dt;
        const float wv  = __expf(-sq * tt * tt);
        const float wsw = __shfl_xor(wv, 32, 64);   /* other half's window */

        /* geometry MFMA -> own-i cuts c0..7 in dg[0..7] */
        const bf16x4 mrow = sM[si][h];
        bf16x8 ag;
        ag[0] = kh ? (__bf16)0.f : mrow[0];
        ag[1] = kh ? (__bf16)0.f : mrow[1];
        ag[2] = kh ? (__bf16)0.f : mrow[2];
        ag[3] = kh ? (__bf16)0.f : mrow[3];
#pragma unroll
        for (int e = 4; e < 8; ++e) ag[e] = (__bf16)0.f;
        const f32x16 dg = __builtin_amdgcn_mfma_f32_32x32x16_bf16(
            ag, bgeo, czero, 0, 0, 0);

        /* u = w * relu(cut); build khalf-mirrored matvec A-frags */
        const __bf16 wb = (__bf16)wsw;
        const __bf16 zb = (__bf16)0.f;
        bf16x8 af0, af1;
#pragma unroll
        for (int e = 0; e < 8; ++e) {
            const __bf16 ub    = (__bf16)(wv * fmaxf(dg[e], 0.f));
            const __bf16 wslot = (e == 0) ? wb : zb;
            af0[e] = kh ? wslot : ub;
            af1[e] = kh ? ub : wslot;
        }

        const f32x16 d0 = __builtin_amdgcn_mfma_f32_32x32x16_bf16(
            af0, bM0, czero, 0, 0, 0);
        const f32x16 d1 = __builtin_amdgcn_mfma_f32_32x32x16_bf16(
            af1, bM1, czero, 0, 0, 0);

        float a0 = 0.f, a1 = 0.f, b0 = 0.f, b1 = 0.f;
#pragma unroll
        for (int r = 0; r < 16; r += 2) {
            a0 = fmaf(fmaxf(d0[r],     0.f), freg[r],     a0);
            a1 = fmaf(fmaxf(d0[r + 1], 0.f), freg[r + 1], a1);
            b0 = fmaf(fmaxf(d1[r],     0.f), freg[r],     b0);
            b1 = fmaf(fmaxf(d1[r + 1], 0.f), freg[r + 1], b1);
        }
        accv[2 * si]     = a0 + a1;
        accv[2 * si + 1] = b0 + b1;
    }

    /* ---- block-level reduction via LDS atomics ---- */
#pragma unroll
    for (int il = 0; il < ICH; ++il)
        atomicAdd(&sacc[il][h], accv[il]);
    __syncthreads();

    /* ---- flush tile to global (ICH*32 = 256 cells) ---- */
    if (t < ICH * 32) {
        const int il0 = t >> 5, h0 = t & 31;
        atomicAdd(&fout[(ibase + il0) * HDIM + h0], sacc[il0][h0]);
    }
}

extern "C" void kernel_launch(void* const* d_in, const int* in_sizes, int n_in,
                              void* d_out, int out_size, void* d_ws, size_t ws_size,
                              hipStream_t stream)
{
    const float* points   = (const float*)d_in[0];
    const float* nuv      = (const float*)d_in[1];
    const float* features = (const float*)d_in[2];
    const float* W_in1    = (const float*)d_in[3];
    const float* b_in1    = (const float*)d_in[4];
    const float* W_in2    = (const float*)d_in[5];
    const float* b_in2    = (const float*)d_in[6];
    const float* g_in_w   = (const float*)d_in[7];
    const float* g_in_b   = (const float*)d_in[8];
    const float* A1       = (const float*)d_in[9];
    const float* A2       = (const float*)d_in[10];
    const float* W_out1   = (const float*)d_in[11];
    const float* b_out1   = (const float*)d_in[12];
    const float* W_out2   = (const float*)d_in[13];
    const float* b_out2   = (const float*)d_in[14];
    const float* g_out_w  = (const float*)d_in[15];
    const float* g_out_b  = (const float*)d_in[16];
    const float* B1       = (const float*)d_in[17];
    const float* B2       = (const float*)d_in[18];

    float* ws    = (float*)d_ws;
    float* t2a   = ws;               /* N*H raw net_in output */
    float* t2b   = ws + 65536;       /* N*H raw net_out output */
    float* fout  = ws + 131072;      /* N*H pairwise accumulator */
    float* ipack = ws + 196608;      /* N*IPK = 98304 */
    float* part1 = ws + 294912;      /* 256 floats */
    float* part2 = ws + 295168;      /* 256 floats */
    float* out   = (float*)d_out;

    /* net_in (+stats partials, +zero fout, +ipack) */
    net2_kernel<IDIM><<<dim3(NPTS / 64), dim3(64), 0, stream>>>(
        features, W_in1, b_in1, W_in2, b_in2, t2a, part1, fout,
        points, nuv, A1, B1, ipack);

    /* all-pairs interaction (GroupNorm of f applied on the fly) */
    pairwise_kernel<<<dim3(NPTS / 256, NPTS / ICH), dim3(512), 0, stream>>>(
        points, nuv, A2, B2, ipack, t2a, part1, g_in_w, g_in_b, fout);

    /* net_out (+stats partials), then final normalize -> out */
    net2_kernel<HDIM><<<dim3(NPTS / 64), dim3(64), 0, stream>>>(
        fout, W_out1, b_out1, W_out2, b_out2, t2b, part2, nullptr,
        nullptr, nullptr, nullptr, nullptr, nullptr);
    gn_apply_kernel<<<dim3(NPTS * HDIM / 256), dim3(256), 0, stream>>>(
        t2b, part2, g_out_w, g_out_b, out);
}